// Round 10
// baseline (569.556 us; speedup 1.0000x reference)
//
#include <hip/hip_runtime.h>
#include <hip/hip_bf16.h>

// ===========================================================================
// GIN link-pred. R9->R10: deeper ILP on the two latency-bound gather kernels.
//  - gemm_gather neighbor loop unroll 4 -> 8 (8 row loads in flight; R9
//    showed unroll 2->4 cut 99->85 us at constant 187 MB FETCH => latency).
//  - edge_dot processes 2 edges per 16-lane group per iter (4 uint4 loads in
//    flight, float2 store).
// Everything else unchanged from R9 (chunk-bucketed sort, bf16 shadow
// activations, W bf16 hi/lo, 128-row streaming GEMM). Requires N < 2^22.
// ===========================================================================

typedef __attribute__((ext_vector_type(8))) short short8v;
typedef __attribute__((ext_vector_type(4))) float float4v;

#define NBLK_SORT 512

__device__ __forceinline__ unsigned short f2bf(float f) {
    union { float f; unsigned u; } v; v.f = f;
    unsigned u = v.u;
    unsigned r = u + 0x7fffu + ((u >> 16) & 1u);   // RNE
    return (unsigned short)(r >> 16);
}
__device__ __forceinline__ float bf2f(unsigned short h) {
    union { unsigned u; float f; } v; v.u = ((unsigned)h) << 16;
    return v.f;
}
__device__ __forceinline__ float bfu_lo(unsigned u) {
    union { unsigned v; float f; } x; x.v = u << 16; return x.f;
}
__device__ __forceinline__ float bfu_hi(unsigned u) {
    union { unsigned v; float f; } x; x.v = u & 0xffff0000u; return x.f;
}
__device__ __forceinline__ unsigned pkbf(float x, float y) {
    __hip_bfloat162 t = __float22bfloat162_rn(float2{x, y});
    union { __hip_bfloat162 b; unsigned u; } c; c.b = t;
    return c.u;
}
__device__ __forceinline__ void addrow(float4& a0, float4& a1, const uint4 u) {
    a0.x += bfu_lo(u.x); a0.y += bfu_hi(u.x);
    a0.z += bfu_lo(u.y); a0.w += bfu_hi(u.y);
    a1.x += bfu_lo(u.z); a1.y += bfu_hi(u.z);
    a1.z += bfu_lo(u.w); a1.w += bfu_hi(u.w);
}

// ---------------------------------------------------------------------------
// Weight prep: 7 128x128 fp32 -> transposed (n-major) bf16 hi/lo splits.
// ---------------------------------------------------------------------------
__global__ __launch_bounds__(256) void prep_w(
    const float* __restrict__ lin_w, const float* __restrict__ W1,
    const float* __restrict__ W2,
    unsigned short* __restrict__ wt_hi, unsigned short* __restrict__ wt_lo)
{
    int idx = blockIdx.x * 256 + threadIdx.x;
    if (idx >= 7 * 16384) return;
    int m = idx >> 14;
    int r = idx & 16383;          // r = k*128 + n
    int k = r >> 7, n = r & 127;
    const float* src = (m == 0) ? lin_w
                     : (m <= 3) ? W1 + (size_t)(m - 1) * 16384
                                : W2 + (size_t)(m - 4) * 16384;
    float w = src[r];
    unsigned short hi = f2bf(w);
    unsigned short lo = f2bf(w - bf2f(hi));
    wt_hi[(size_t)m * 16384 + n * 128 + k] = hi;   // [n][k]
    wt_lo[(size_t)m * 16384 + n * 128 + k] = lo;
}

// ---------------------------------------------------------------------------
// Bucketed counting sort -> CSR (chunk = 1024 dst nodes).
// ---------------------------------------------------------------------------
__global__ __launch_bounds__(256) void chunk_count(
    const int* __restrict__ dst, int* __restrict__ cnt, int E, int nbc)
{
    __shared__ int l[1024];
    const int tid = threadIdx.x, b = blockIdx.x;
    for (int i = tid; i < nbc; i += 256) l[i] = 0;
    __syncthreads();
    const int per = (E + gridDim.x - 1) / gridDim.x;
    const int e0 = b * per, e1 = min(E, e0 + per);
    for (int e = e0 + tid; e < e1; e += 256)
        atomicAdd(&l[dst[e] >> 10], 1);
    __syncthreads();
    for (int c = tid; c < nbc; c += 256) cnt[c * gridDim.x + b] = l[c];
}

__global__ __launch_bounds__(512) void scan_blocks(
    int* __restrict__ cnt, int* __restrict__ ctot)
{
    __shared__ int sh[512];
    const int c = blockIdx.x, t = threadIdx.x;
    const int v = cnt[c * NBLK_SORT + t];
    sh[t] = v;
    __syncthreads();
    for (int off = 1; off < 512; off <<= 1) {
        int x = (t >= off) ? sh[t - off] : 0;
        __syncthreads();
        sh[t] += x;
        __syncthreads();
    }
    cnt[c * NBLK_SORT + t] = sh[t] - v;   // exclusive
    if (t == 511) ctot[c] = sh[511];
}

__global__ void scan_ctot(const int* __restrict__ ctot,
                          int* __restrict__ chunkBase, int nbc)
{
    if (threadIdx.x == 0 && blockIdx.x == 0) {
        int acc = 0;
        for (int c = 0; c < nbc; c++) { chunkBase[c] = acc; acc += ctot[c]; }
        chunkBase[nbc] = acc;
    }
}

__global__ __launch_bounds__(256) void bucket_scatter(
    const int* __restrict__ src, const int* __restrict__ dst,
    const int* __restrict__ cnt, const int* __restrict__ chunkBase,
    int* __restrict__ temp, int E, int nbc)
{
    __shared__ int lcur[1024];
    const int tid = threadIdx.x, b = blockIdx.x;
    for (int c = tid; c < nbc; c += 256)
        lcur[c] = cnt[c * gridDim.x + b] + chunkBase[c];
    __syncthreads();
    const int per = (E + gridDim.x - 1) / gridDim.x;
    const int e0 = b * per, e1 = min(E, e0 + per);
    for (int e = e0 + tid; e < e1; e += 256) {
        const int d = dst[e];
        const int pos = atomicAdd(&lcur[d >> 10], 1);
        temp[pos] = ((d & 1023) << 22) | src[e];
    }
}

__global__ __launch_bounds__(256) void chunk_place(
    const int* __restrict__ temp, const int* __restrict__ chunkBase,
    int* __restrict__ col, int* __restrict__ deg, int* __restrict__ rowptr,
    int N)
{
    __shared__ int lcnt[1024];
    __shared__ int lcur[1024];
    __shared__ int sh[256];
    const int tid = threadIdx.x, c = blockIdx.x;
    const int s = chunkBase[c], e2 = chunkBase[c + 1];

    for (int i = tid; i < 1024; i += 256) lcnt[i] = 0;
    __syncthreads();
    for (int i = s + tid; i < e2; i += 256)
        atomicAdd(&lcnt[((unsigned)temp[i]) >> 22], 1);
    __syncthreads();

    const int b4 = tid * 4;
    const int v0 = lcnt[b4], v1 = lcnt[b4 + 1], v2 = lcnt[b4 + 2], v3 = lcnt[b4 + 3];
    const int ts = v0 + v1 + v2 + v3;
    sh[tid] = ts;
    __syncthreads();
    for (int off = 1; off < 256; off <<= 1) {
        int x = (tid >= off) ? sh[tid - off] : 0;
        __syncthreads();
        sh[tid] += x;
        __syncthreads();
    }
    const int run = sh[tid] - ts;
    lcur[b4]     = s + run;
    lcur[b4 + 1] = s + run + v0;
    lcur[b4 + 2] = s + run + v0 + v1;
    lcur[b4 + 3] = s + run + v0 + v1 + v2;
    const int node0 = c << 10;
    if (node0 + b4 < N)     { deg[node0 + b4]     = v0; rowptr[node0 + b4]     = lcur[b4]; }
    if (node0 + b4 + 1 < N) { deg[node0 + b4 + 1] = v1; rowptr[node0 + b4 + 1] = lcur[b4 + 1]; }
    if (node0 + b4 + 2 < N) { deg[node0 + b4 + 2] = v2; rowptr[node0 + b4 + 2] = lcur[b4 + 2]; }
    if (node0 + b4 + 3 < N) { deg[node0 + b4 + 3] = v3; rowptr[node0 + b4 + 3] = lcur[b4 + 3]; }
    __syncthreads();

    for (int i = s + tid; i < e2; i += 256) {
        const unsigned p = (unsigned)temp[i];
        const int pos = atomicAdd(&lcur[p >> 22], 1);
        col[pos] = (int)(p & 0x3FFFFFu);
    }
}

// ---------------------------------------------------------------------------
// Gather-GEMM (gemm1): hbZ[N,128] = (h + sum_j h[col]) @ W + b, BN partials.
// Neighbor loop unrolled x8 (8 independent 16B row loads in flight).
// ---------------------------------------------------------------------------
__global__ __launch_bounds__(256) void gemm_gather(
    const unsigned short* __restrict__ AinB,
    const int* __restrict__ rowptr, const int* __restrict__ deg,
    const int* __restrict__ col,
    const unsigned short* __restrict__ Wh, const unsigned short* __restrict__ Wl,
    const float* __restrict__ bias,
    unsigned short* __restrict__ outb, float* __restrict__ part, int N)
{
    __shared__ __align__(16) unsigned short As[64][136];
    const int tid = threadIdx.x;
    const int row0 = blockIdx.x * 64;

    const int g = tid >> 4;
    const int l = tid & 15;
    #pragma unroll
    for (int rr = 0; rr < 4; rr++) {
        const int r = g + rr * 16;
        const int row = row0 + r;
        float4 a0 = make_float4(0.f, 0.f, 0.f, 0.f);
        float4 a1 = make_float4(0.f, 0.f, 0.f, 0.f);
        if (row < N) {
            const uint4 su = *(const uint4*)(AinB + (size_t)row * 128 + l * 8);
            addrow(a0, a1, su);
            const int start = rowptr[row];
            const int cnt = deg[row];
            int j = 0;
            for (; j + 7 < cnt; j += 8) {
                const int c0i = col[start + j];
                const int c1i = col[start + j + 1];
                const int c2i = col[start + j + 2];
                const int c3i = col[start + j + 3];
                const int c4i = col[start + j + 4];
                const int c5i = col[start + j + 5];
                const int c6i = col[start + j + 6];
                const int c7i = col[start + j + 7];
                const uint4 u0 = *(const uint4*)(AinB + (size_t)c0i * 128 + l * 8);
                const uint4 u1 = *(const uint4*)(AinB + (size_t)c1i * 128 + l * 8);
                const uint4 u2 = *(const uint4*)(AinB + (size_t)c2i * 128 + l * 8);
                const uint4 u3 = *(const uint4*)(AinB + (size_t)c3i * 128 + l * 8);
                const uint4 u4 = *(const uint4*)(AinB + (size_t)c4i * 128 + l * 8);
                const uint4 u5 = *(const uint4*)(AinB + (size_t)c5i * 128 + l * 8);
                const uint4 u6 = *(const uint4*)(AinB + (size_t)c6i * 128 + l * 8);
                const uint4 u7 = *(const uint4*)(AinB + (size_t)c7i * 128 + l * 8);
                addrow(a0, a1, u0); addrow(a0, a1, u1);
                addrow(a0, a1, u2); addrow(a0, a1, u3);
                addrow(a0, a1, u4); addrow(a0, a1, u5);
                addrow(a0, a1, u6); addrow(a0, a1, u7);
            }
            if (j + 3 < cnt) {
                const int c0i = col[start + j];
                const int c1i = col[start + j + 1];
                const int c2i = col[start + j + 2];
                const int c3i = col[start + j + 3];
                const uint4 u0 = *(const uint4*)(AinB + (size_t)c0i * 128 + l * 8);
                const uint4 u1 = *(const uint4*)(AinB + (size_t)c1i * 128 + l * 8);
                const uint4 u2 = *(const uint4*)(AinB + (size_t)c2i * 128 + l * 8);
                const uint4 u3 = *(const uint4*)(AinB + (size_t)c3i * 128 + l * 8);
                addrow(a0, a1, u0); addrow(a0, a1, u1);
                addrow(a0, a1, u2); addrow(a0, a1, u3);
                j += 4;
            }
            for (; j < cnt; j++) {
                const int c0i = col[start + j];
                const uint4 u0 = *(const uint4*)(AinB + (size_t)c0i * 128 + l * 8);
                addrow(a0, a1, u0);
            }
        }
        uint4 uh;
        uh.x = pkbf(a0.x, a0.y);
        uh.y = pkbf(a0.z, a0.w);
        uh.z = pkbf(a1.x, a1.y);
        uh.w = pkbf(a1.z, a1.w);
        *(uint4*)&As[r][l * 8] = uh;
    }
    __syncthreads();

    const int w    = tid >> 6;
    const int lane = tid & 63;
    const int ln   = lane & 15;
    const int lq   = lane >> 4;
    const int c0   = w * 32;

    float4v acc[4][2];
    #pragma unroll
    for (int nt = 0; nt < 2; nt++) {
        const float bv = bias[c0 + nt * 16 + ln];
        #pragma unroll
        for (int mt = 0; mt < 4; mt++) acc[mt][nt] = (float4v){bv, bv, bv, bv};
    }

    #pragma unroll
    for (int kc = 0; kc < 4; kc++) {
        const size_t b0 = (size_t)(c0 + ln) * 128 + kc * 32 + lq * 8;
        const size_t b1 = (size_t)(c0 + 16 + ln) * 128 + kc * 32 + lq * 8;
        const short8v bh0 = *(const short8v*)&Wh[b0];
        const short8v bl0 = *(const short8v*)&Wl[b0];
        const short8v bh1 = *(const short8v*)&Wh[b1];
        const short8v bl1 = *(const short8v*)&Wl[b1];
        #pragma unroll
        for (int mt = 0; mt < 4; mt++) {
            const short8v ah = *(const short8v*)&As[mt * 16 + ln][kc * 32 + lq * 8];
            acc[mt][0] = __builtin_amdgcn_mfma_f32_16x16x32_bf16(ah, bh0, acc[mt][0], 0, 0, 0);
            acc[mt][0] = __builtin_amdgcn_mfma_f32_16x16x32_bf16(ah, bl0, acc[mt][0], 0, 0, 0);
            acc[mt][1] = __builtin_amdgcn_mfma_f32_16x16x32_bf16(ah, bh1, acc[mt][1], 0, 0, 0);
            acc[mt][1] = __builtin_amdgcn_mfma_f32_16x16x32_bf16(ah, bl1, acc[mt][1], 0, 0, 0);
        }
    }

    #pragma unroll
    for (int mt = 0; mt < 4; mt++) {
        #pragma unroll
        for (int nt = 0; nt < 2; nt++) {
            const int colv = c0 + nt * 16 + ln;
            #pragma unroll
            for (int i = 0; i < 4; i++) {
                const int row = row0 + mt * 16 + lq * 4 + i;
                if (row < N)
                    outb[(size_t)row * 128 + colv] = f2bf(acc[mt][nt][i]);
            }
        }
    }

    // BN stats partials (pre-activation z); wave owns its 32 cols
    #pragma unroll
    for (int nt = 0; nt < 2; nt++) {
        float s = 0.f, q = 0.f;
        #pragma unroll
        for (int mt = 0; mt < 4; mt++) {
            #pragma unroll
            for (int i = 0; i < 4; i++) {
                const int row = row0 + mt * 16 + lq * 4 + i;
                if (row < N) { const float v = acc[mt][nt][i]; s += v; q += v * v; }
            }
        }
        s += __shfl_xor(s, 16); s += __shfl_xor(s, 32);
        q += __shfl_xor(q, 16); q += __shfl_xor(q, 32);
        if (lq == 0) {
            const int colv = c0 + nt * 16 + ln;
            part[(size_t)colv * gridDim.x + blockIdx.x] = s;
            part[(size_t)(128 + colv) * gridDim.x + blockIdx.x] = q;
        }
    }
}

// ---------------------------------------------------------------------------
// Streaming GEMM (lin, gemm2): 128-row tile, acc[8][2].
// flags: 1=BN apply+relu on staged input, 2=relu out, 64=bf16 input.
// ---------------------------------------------------------------------------
__global__ __launch_bounds__(256) void gemm_stream(
    const float* __restrict__ Ain32, const unsigned short* __restrict__ AinB,
    const unsigned short* __restrict__ Wh, const unsigned short* __restrict__ Wl,
    const float* __restrict__ bias, const float* __restrict__ ss,
    unsigned short* __restrict__ outb, int N, int flags)
{
    __shared__ __align__(16) unsigned short As[128][136];
    const int tid = threadIdx.x;
    const int row0 = blockIdx.x * 128;

    if (flags & 64) {
        for (int i = tid; i < 128 * 16; i += 256) {
            const int r = i >> 4, c8 = i & 15;
            const int row = row0 + r;
            uint4 u = make_uint4(0, 0, 0, 0);
            if (row < N) {
                u = *(const uint4*)(AinB + (size_t)row * 128 + c8 * 8);
                if (flags & 1) {
                    float4 v0, v1;
                    v0.x = bfu_lo(u.x); v0.y = bfu_hi(u.x);
                    v0.z = bfu_lo(u.y); v0.w = bfu_hi(u.y);
                    v1.x = bfu_lo(u.z); v1.y = bfu_hi(u.z);
                    v1.z = bfu_lo(u.w); v1.w = bfu_hi(u.w);
                    const float4 sc0 = ((const float4*)ss)[c8 * 2];
                    const float4 sc1 = ((const float4*)ss)[c8 * 2 + 1];
                    const float4 sh0 = ((const float4*)(ss + 128))[c8 * 2];
                    const float4 sh1 = ((const float4*)(ss + 128))[c8 * 2 + 1];
                    v0.x = fmaxf(v0.x * sc0.x + sh0.x, 0.f);
                    v0.y = fmaxf(v0.y * sc0.y + sh0.y, 0.f);
                    v0.z = fmaxf(v0.z * sc0.z + sh0.z, 0.f);
                    v0.w = fmaxf(v0.w * sc0.w + sh0.w, 0.f);
                    v1.x = fmaxf(v1.x * sc1.x + sh1.x, 0.f);
                    v1.y = fmaxf(v1.y * sc1.y + sh1.y, 0.f);
                    v1.z = fmaxf(v1.z * sc1.z + sh1.z, 0.f);
                    v1.w = fmaxf(v1.w * sc1.w + sh1.w, 0.f);
                    u.x = pkbf(v0.x, v0.y);
                    u.y = pkbf(v0.z, v0.w);
                    u.z = pkbf(v1.x, v1.y);
                    u.w = pkbf(v1.z, v1.w);
                }
            }
            *(uint4*)&As[r][c8 * 8] = u;
        }
    } else {
        for (int i = tid; i < 128 * 32; i += 256) {
            const int r = i >> 5, c4 = i & 31;
            const int row = row0 + r;
            float4 v = make_float4(0.f, 0.f, 0.f, 0.f);
            if (row < N) v = ((const float4*)(Ain32 + (size_t)row * 128))[c4];
            uint2 uh;
            uh.x = pkbf(v.x, v.y);
            uh.y = pkbf(v.z, v.w);
            *(uint2*)&As[r][c4 * 4] = uh;
        }
    }
    __syncthreads();

    const int w    = tid >> 6;
    const int lane = tid & 63;
    const int ln   = lane & 15;
    const int lq   = lane >> 4;
    const int c0   = w * 32;

    float4v acc[8][2];
    #pragma unroll
    for (int nt = 0; nt < 2; nt++) {
        const float bv = bias[c0 + nt * 16 + ln];
        #pragma unroll
        for (int mt = 0; mt < 8; mt++) acc[mt][nt] = (float4v){bv, bv, bv, bv};
    }

    #pragma unroll
    for (int kc = 0; kc < 4; kc++) {
        const size_t b0 = (size_t)(c0 + ln) * 128 + kc * 32 + lq * 8;
        const size_t b1 = (size_t)(c0 + 16 + ln) * 128 + kc * 32 + lq * 8;
        const short8v bh0 = *(const short8v*)&Wh[b0];
        const short8v bl0 = *(const short8v*)&Wl[b0];
        const short8v bh1 = *(const short8v*)&Wh[b1];
        const short8v bl1 = *(const short8v*)&Wl[b1];
        #pragma unroll
        for (int mt = 0; mt < 8; mt++) {
            const short8v ah = *(const short8v*)&As[mt * 16 + ln][kc * 32 + lq * 8];
            acc[mt][0] = __builtin_amdgcn_mfma_f32_16x16x32_bf16(ah, bh0, acc[mt][0], 0, 0, 0);
            acc[mt][0] = __builtin_amdgcn_mfma_f32_16x16x32_bf16(ah, bl0, acc[mt][0], 0, 0, 0);
            acc[mt][1] = __builtin_amdgcn_mfma_f32_16x16x32_bf16(ah, bh1, acc[mt][1], 0, 0, 0);
            acc[mt][1] = __builtin_amdgcn_mfma_f32_16x16x32_bf16(ah, bl1, acc[mt][1], 0, 0, 0);
        }
    }

    #pragma unroll
    for (int mt = 0; mt < 8; mt++) {
        #pragma unroll
        for (int nt = 0; nt < 2; nt++) {
            const int colv = c0 + nt * 16 + ln;
            #pragma unroll
            for (int i = 0; i < 4; i++) {
                const int row = row0 + mt * 16 + lq * 4 + i;
                if (row < N) {
                    float v = acc[mt][nt][i];
                    if (flags & 2) v = fmaxf(v, 0.f);
                    outb[(size_t)row * 128 + colv] = f2bf(v);
                }
            }
        }
    }
}

// ---------------------------------------------------------------------------
// BN finalize: reduce partials -> scale[c], shift[c]. grid=128 (1/channel).
// ---------------------------------------------------------------------------
__global__ __launch_bounds__(256) void bn_finalize(
    const float* __restrict__ part, int nblk, float invN,
    const float* __restrict__ gamma, const float* __restrict__ beta,
    float* __restrict__ ss)
{
    __shared__ float shs[256], shq[256];
    const int c = blockIdx.x, t = threadIdx.x;
    float s = 0.f, q = 0.f;
    for (int b = t; b < nblk; b += 256) {
        s += part[(size_t)c * nblk + b];
        q += part[(size_t)(128 + c) * nblk + b];
    }
    shs[t] = s; shq[t] = q;
    __syncthreads();
    for (int o = 128; o > 0; o >>= 1) {
        if (t < o) { shs[t] += shs[t + o]; shq[t] += shq[t + o]; }
        __syncthreads();
    }
    if (t == 0) {
        const float mu = shs[0] * invN;
        const float var = shq[0] * invN - mu * mu;
        const float sc = rsqrtf(fmaxf(var, 0.f) + 1e-5f) * gamma[c];
        ss[c] = sc;
        ss[128 + c] = beta[c] - mu * sc;
    }
}

// ---------------------------------------------------------------------------
// Classifier: out[e] = dot(hb[ia[e]], hb[ib[e]]). 2 edges per 16-lane group
// per iteration (4 independent 16B loads in flight), float2 store.
// ---------------------------------------------------------------------------
__global__ __launch_bounds__(256) void edge_dot(
    const unsigned short* __restrict__ hb, const int* __restrict__ ia,
    const int* __restrict__ ib, float* __restrict__ out, int EL)
{
    const int stride = gridDim.x * blockDim.x;
    const int npair = (EL + 1) >> 1;
    const long long total = (long long)npair * 16;
    for (long long i = (long long)blockIdx.x * blockDim.x + threadIdx.x; i < total; i += stride) {
        const int p = (int)(i >> 4);
        const int l = (int)(i & 15);
        const int e0 = p * 2;
        const int e1 = e0 + 1;
        const int a0i = ia[e0], b0i = ib[e0];
        const uint4 ua0 = *(const uint4*)(hb + (size_t)a0i * 128 + l * 8);
        const uint4 ub0 = *(const uint4*)(hb + (size_t)b0i * 128 + l * 8);
        uint4 ua1 = make_uint4(0, 0, 0, 0), ub1 = make_uint4(0, 0, 0, 0);
        const bool has1 = (e1 < EL);
        if (has1) {
            const int a1i = ia[e1], b1i = ib[e1];
            ua1 = *(const uint4*)(hb + (size_t)a1i * 128 + l * 8);
            ub1 = *(const uint4*)(hb + (size_t)b1i * 128 + l * 8);
        }
        float d0 = bfu_lo(ua0.x) * bfu_lo(ub0.x) + bfu_hi(ua0.x) * bfu_hi(ub0.x)
                 + bfu_lo(ua0.y) * bfu_lo(ub0.y) + bfu_hi(ua0.y) * bfu_hi(ub0.y)
                 + bfu_lo(ua0.z) * bfu_lo(ub0.z) + bfu_hi(ua0.z) * bfu_hi(ub0.z)
                 + bfu_lo(ua0.w) * bfu_lo(ub0.w) + bfu_hi(ua0.w) * bfu_hi(ub0.w);
        float d1 = bfu_lo(ua1.x) * bfu_lo(ub1.x) + bfu_hi(ua1.x) * bfu_hi(ub1.x)
                 + bfu_lo(ua1.y) * bfu_lo(ub1.y) + bfu_hi(ua1.y) * bfu_hi(ub1.y)
                 + bfu_lo(ua1.z) * bfu_lo(ub1.z) + bfu_hi(ua1.z) * bfu_hi(ub1.z)
                 + bfu_lo(ua1.w) * bfu_lo(ub1.w) + bfu_hi(ua1.w) * bfu_hi(ub1.w);
        d0 += __shfl_xor(d0, 1); d1 += __shfl_xor(d1, 1);
        d0 += __shfl_xor(d0, 2); d1 += __shfl_xor(d1, 2);
        d0 += __shfl_xor(d0, 4); d1 += __shfl_xor(d1, 4);
        d0 += __shfl_xor(d0, 8); d1 += __shfl_xor(d1, 8);
        if (l == 0) {
            if (has1) *(float2*)(out + e0) = make_float2(d0, d1);
            else      out[e0] = d0;
        }
    }
}

extern "C" void kernel_launch(void* const* d_in, const int* in_sizes, int n_in,
                              void* d_out, int out_size, void* d_ws, size_t ws_size,
                              hipStream_t stream)
{
    const float* x     = (const float*)d_in[0];
    const float* lin_w = (const float*)d_in[1];
    const float* lin_b = (const float*)d_in[2];
    const float* W1    = (const float*)d_in[3];
    const float* b1    = (const float*)d_in[4];
    const float* gamma = (const float*)d_in[5];
    const float* beta  = (const float*)d_in[6];
    const float* W2    = (const float*)d_in[7];
    const float* b2    = (const float*)d_in[8];
    const int*   ei    = (const int*)d_in[9];
    const int*   eli   = (const int*)d_in[10];
    float* out = (float*)d_out;

    const int N  = in_sizes[0] / 128;
    const int E  = in_sizes[9] / 2;
    const int EL = in_sizes[10] / 2;
    const size_t nd = (size_t)N * 128;
    const int nbc = (N + 1023) >> 10;            // 1024-node chunks
    const int g_grid = (N + 63) / 64;            // gather-gemm grid
    const int s_grid = (N + 127) / 128;          // streaming-gemm grid

    // ws: hbH | hbZ | deg | rowptr | cnt | ctot | chunkBase | temp | col | wts | part | ss
    unsigned short* hbH = (unsigned short*)d_ws;
    unsigned short* hbZ = hbH + nd;
    int*   deg    = (int*)(hbZ + nd);
    int*   rowptr = deg + N;
    int*   cnt    = rowptr + N;                  // [nbc][NBLK_SORT]
    int*   ctot   = cnt + (size_t)nbc * NBLK_SORT;
    int*   chunkBase = ctot + nbc;
    int*   temp   = chunkBase + nbc + 1;
    int*   col    = temp + E;
    unsigned short* wt_hi = (unsigned short*)(col + E);
    unsigned short* wt_lo = wt_hi + 7 * 16384;
    float* part   = (float*)(wt_lo + 7 * 16384);
    float* ss     = part + (size_t)256 * g_grid;

    const float invN = 1.0f / (float)N;

    // ---- weight prep + bucketed CSR build ----
    prep_w<<<448, 256, 0, stream>>>(lin_w, W1, W2, wt_hi, wt_lo);
    chunk_count<<<NBLK_SORT, 256, 0, stream>>>(ei + E, cnt, E, nbc);
    scan_blocks<<<nbc, 512, 0, stream>>>(cnt, ctot);
    scan_ctot<<<1, 64, 0, stream>>>(ctot, chunkBase, nbc);
    bucket_scatter<<<NBLK_SORT, 256, 0, stream>>>(ei, ei + E, cnt, chunkBase, temp, E, nbc);
    chunk_place<<<nbc, 256, 0, stream>>>(temp, chunkBase, col, deg, rowptr, N);

    // ---- h = x @ lin_w + lin_b  -> hbH (bf16) ----
    gemm_stream<<<s_grid, 256, 0, stream>>>(x, nullptr, wt_hi, wt_lo, lin_b, ss,
                                            hbH, N, 0);

    for (int l = 0; l < 3; l++) {
        const unsigned short* w1h = wt_hi + (size_t)(1 + l) * 16384;
        const unsigned short* w1l = wt_lo + (size_t)(1 + l) * 16384;
        const unsigned short* w2h = wt_hi + (size_t)(4 + l) * 16384;
        const unsigned short* w2l = wt_lo + (size_t)(4 + l) * 16384;
        // z = (h + agg) @ W1 + b1 : gather from hbH, write hbZ, BN partials
        gemm_gather<<<g_grid, 256, 0, stream>>>(hbH, rowptr, deg, col,
                                                w1h, w1l, b1 + (size_t)l * 128,
                                                hbZ, part, N);
        bn_finalize<<<128, 256, 0, stream>>>(part, g_grid, invN,
                                             gamma + (size_t)l * 128,
                                             beta + (size_t)l * 128, ss);
        // h = relu(bn(z) @ W2 + b2) : stage hbZ + BN + relu, write hbH
        gemm_stream<<<s_grid, 256, 0, stream>>>(nullptr, hbZ, w2h, w2l,
                                                b2 + (size_t)l * 128, ss,
                                                hbH, N, 1 | 2 | 64);
    }

    edge_dot<<<8192, 256, 0, stream>>>(hbH, eli, eli + EL, out, EL);
}

// Round 11
// 558.113 us; speedup vs baseline: 1.0205x; 1.0205x over previous
//
#include <hip/hip_runtime.h>
#include <hip/hip_bf16.h>

// ===========================================================================
// GIN link-pred. R10->R11:
//  - gemm_gather neighbor unroll reverted 8 -> 4 (R10: VGPR 68 cut occupancy
//    24.6% vs 31%, gather 85->93 us; wave count beats per-wave ILP here).
//  - gather tile 64 -> 32 rows (grid 1563 -> 3125 blocks ~ 12.2/CU vs HW
//    residency cap 8 blocks/CU: saturate the cap + halve tail quantization).
//  - edge_dot keeps 2-edges-per-group form (R10: helped ~5 us).
// Everything else unchanged from R9 (chunk-bucketed sort, bf16 shadow
// activations, W bf16 hi/lo, 128-row streaming GEMM). Requires N < 2^22.
// ===========================================================================

typedef __attribute__((ext_vector_type(8))) short short8v;
typedef __attribute__((ext_vector_type(4))) float float4v;

#define NBLK_SORT 512

__device__ __forceinline__ unsigned short f2bf(float f) {
    union { float f; unsigned u; } v; v.f = f;
    unsigned u = v.u;
    unsigned r = u + 0x7fffu + ((u >> 16) & 1u);   // RNE
    return (unsigned short)(r >> 16);
}
__device__ __forceinline__ float bf2f(unsigned short h) {
    union { unsigned u; float f; } v; v.u = ((unsigned)h) << 16;
    return v.f;
}
__device__ __forceinline__ float bfu_lo(unsigned u) {
    union { unsigned v; float f; } x; x.v = u << 16; return x.f;
}
__device__ __forceinline__ float bfu_hi(unsigned u) {
    union { unsigned v; float f; } x; x.v = u & 0xffff0000u; return x.f;
}
__device__ __forceinline__ unsigned pkbf(float x, float y) {
    __hip_bfloat162 t = __float22bfloat162_rn(float2{x, y});
    union { __hip_bfloat162 b; unsigned u; } c; c.b = t;
    return c.u;
}
__device__ __forceinline__ void addrow(float4& a0, float4& a1, const uint4 u) {
    a0.x += bfu_lo(u.x); a0.y += bfu_hi(u.x);
    a0.z += bfu_lo(u.y); a0.w += bfu_hi(u.y);
    a1.x += bfu_lo(u.z); a1.y += bfu_hi(u.z);
    a1.z += bfu_lo(u.w); a1.w += bfu_hi(u.w);
}

// ---------------------------------------------------------------------------
// Weight prep: 7 128x128 fp32 -> transposed (n-major) bf16 hi/lo splits.
// ---------------------------------------------------------------------------
__global__ __launch_bounds__(256) void prep_w(
    const float* __restrict__ lin_w, const float* __restrict__ W1,
    const float* __restrict__ W2,
    unsigned short* __restrict__ wt_hi, unsigned short* __restrict__ wt_lo)
{
    int idx = blockIdx.x * 256 + threadIdx.x;
    if (idx >= 7 * 16384) return;
    int m = idx >> 14;
    int r = idx & 16383;          // r = k*128 + n
    int k = r >> 7, n = r & 127;
    const float* src = (m == 0) ? lin_w
                     : (m <= 3) ? W1 + (size_t)(m - 1) * 16384
                                : W2 + (size_t)(m - 4) * 16384;
    float w = src[r];
    unsigned short hi = f2bf(w);
    unsigned short lo = f2bf(w - bf2f(hi));
    wt_hi[(size_t)m * 16384 + n * 128 + k] = hi;   // [n][k]
    wt_lo[(size_t)m * 16384 + n * 128 + k] = lo;
}

// ---------------------------------------------------------------------------
// Bucketed counting sort -> CSR (chunk = 1024 dst nodes).
// ---------------------------------------------------------------------------
__global__ __launch_bounds__(256) void chunk_count(
    const int* __restrict__ dst, int* __restrict__ cnt, int E, int nbc)
{
    __shared__ int l[1024];
    const int tid = threadIdx.x, b = blockIdx.x;
    for (int i = tid; i < nbc; i += 256) l[i] = 0;
    __syncthreads();
    const int per = (E + gridDim.x - 1) / gridDim.x;
    const int e0 = b * per, e1 = min(E, e0 + per);
    for (int e = e0 + tid; e < e1; e += 256)
        atomicAdd(&l[dst[e] >> 10], 1);
    __syncthreads();
    for (int c = tid; c < nbc; c += 256) cnt[c * gridDim.x + b] = l[c];
}

__global__ __launch_bounds__(512) void scan_blocks(
    int* __restrict__ cnt, int* __restrict__ ctot)
{
    __shared__ int sh[512];
    const int c = blockIdx.x, t = threadIdx.x;
    const int v = cnt[c * NBLK_SORT + t];
    sh[t] = v;
    __syncthreads();
    for (int off = 1; off < 512; off <<= 1) {
        int x = (t >= off) ? sh[t - off] : 0;
        __syncthreads();
        sh[t] += x;
        __syncthreads();
    }
    cnt[c * NBLK_SORT + t] = sh[t] - v;   // exclusive
    if (t == 511) ctot[c] = sh[511];
}

__global__ void scan_ctot(const int* __restrict__ ctot,
                          int* __restrict__ chunkBase, int nbc)
{
    if (threadIdx.x == 0 && blockIdx.x == 0) {
        int acc = 0;
        for (int c = 0; c < nbc; c++) { chunkBase[c] = acc; acc += ctot[c]; }
        chunkBase[nbc] = acc;
    }
}

__global__ __launch_bounds__(256) void bucket_scatter(
    const int* __restrict__ src, const int* __restrict__ dst,
    const int* __restrict__ cnt, const int* __restrict__ chunkBase,
    int* __restrict__ temp, int E, int nbc)
{
    __shared__ int lcur[1024];
    const int tid = threadIdx.x, b = blockIdx.x;
    for (int c = tid; c < nbc; c += 256)
        lcur[c] = cnt[c * gridDim.x + b] + chunkBase[c];
    __syncthreads();
    const int per = (E + gridDim.x - 1) / gridDim.x;
    const int e0 = b * per, e1 = min(E, e0 + per);
    for (int e = e0 + tid; e < e1; e += 256) {
        const int d = dst[e];
        const int pos = atomicAdd(&lcur[d >> 10], 1);
        temp[pos] = ((d & 1023) << 22) | src[e];
    }
}

__global__ __launch_bounds__(256) void chunk_place(
    const int* __restrict__ temp, const int* __restrict__ chunkBase,
    int* __restrict__ col, int* __restrict__ deg, int* __restrict__ rowptr,
    int N)
{
    __shared__ int lcnt[1024];
    __shared__ int lcur[1024];
    __shared__ int sh[256];
    const int tid = threadIdx.x, c = blockIdx.x;
    const int s = chunkBase[c], e2 = chunkBase[c + 1];

    for (int i = tid; i < 1024; i += 256) lcnt[i] = 0;
    __syncthreads();
    for (int i = s + tid; i < e2; i += 256)
        atomicAdd(&lcnt[((unsigned)temp[i]) >> 22], 1);
    __syncthreads();

    const int b4 = tid * 4;
    const int v0 = lcnt[b4], v1 = lcnt[b4 + 1], v2 = lcnt[b4 + 2], v3 = lcnt[b4 + 3];
    const int ts = v0 + v1 + v2 + v3;
    sh[tid] = ts;
    __syncthreads();
    for (int off = 1; off < 256; off <<= 1) {
        int x = (tid >= off) ? sh[tid - off] : 0;
        __syncthreads();
        sh[tid] += x;
        __syncthreads();
    }
    const int run = sh[tid] - ts;
    lcur[b4]     = s + run;
    lcur[b4 + 1] = s + run + v0;
    lcur[b4 + 2] = s + run + v0 + v1;
    lcur[b4 + 3] = s + run + v0 + v1 + v2;
    const int node0 = c << 10;
    if (node0 + b4 < N)     { deg[node0 + b4]     = v0; rowptr[node0 + b4]     = lcur[b4]; }
    if (node0 + b4 + 1 < N) { deg[node0 + b4 + 1] = v1; rowptr[node0 + b4 + 1] = lcur[b4 + 1]; }
    if (node0 + b4 + 2 < N) { deg[node0 + b4 + 2] = v2; rowptr[node0 + b4 + 2] = lcur[b4 + 2]; }
    if (node0 + b4 + 3 < N) { deg[node0 + b4 + 3] = v3; rowptr[node0 + b4 + 3] = lcur[b4 + 3]; }
    __syncthreads();

    for (int i = s + tid; i < e2; i += 256) {
        const unsigned p = (unsigned)temp[i];
        const int pos = atomicAdd(&lcur[p >> 22], 1);
        col[pos] = (int)(p & 0x3FFFFFu);
    }
}

// ---------------------------------------------------------------------------
// Gather-GEMM (gemm1): hbZ[N,128] = (h + sum_j h[col]) @ W + b, BN partials.
// 32-row tile (3125 blocks ~ 12/CU -> saturate 8-block/CU residency cap).
// Neighbor loop unroll x4 (measured-best: R9 85 us; x8 regressed via VGPR).
// ---------------------------------------------------------------------------
__global__ __launch_bounds__(256) void gemm_gather(
    const unsigned short* __restrict__ AinB,
    const int* __restrict__ rowptr, const int* __restrict__ deg,
    const int* __restrict__ col,
    const unsigned short* __restrict__ Wh, const unsigned short* __restrict__ Wl,
    const float* __restrict__ bias,
    unsigned short* __restrict__ outb, float* __restrict__ part, int N)
{
    __shared__ __align__(16) unsigned short As[32][136];
    const int tid = threadIdx.x;
    const int row0 = blockIdx.x * 32;

    const int g = tid >> 4;
    const int l = tid & 15;
    #pragma unroll
    for (int rr = 0; rr < 2; rr++) {
        const int r = g + rr * 16;
        const int row = row0 + r;
        float4 a0 = make_float4(0.f, 0.f, 0.f, 0.f);
        float4 a1 = make_float4(0.f, 0.f, 0.f, 0.f);
        if (row < N) {
            const uint4 su = *(const uint4*)(AinB + (size_t)row * 128 + l * 8);
            addrow(a0, a1, su);
            const int start = rowptr[row];
            const int cnt = deg[row];
            int j = 0;
            for (; j + 3 < cnt; j += 4) {
                const int c0i = col[start + j];
                const int c1i = col[start + j + 1];
                const int c2i = col[start + j + 2];
                const int c3i = col[start + j + 3];
                const uint4 u0 = *(const uint4*)(AinB + (size_t)c0i * 128 + l * 8);
                const uint4 u1 = *(const uint4*)(AinB + (size_t)c1i * 128 + l * 8);
                const uint4 u2 = *(const uint4*)(AinB + (size_t)c2i * 128 + l * 8);
                const uint4 u3 = *(const uint4*)(AinB + (size_t)c3i * 128 + l * 8);
                addrow(a0, a1, u0); addrow(a0, a1, u1);
                addrow(a0, a1, u2); addrow(a0, a1, u3);
            }
            for (; j < cnt; j++) {
                const int c0i = col[start + j];
                const uint4 u0 = *(const uint4*)(AinB + (size_t)c0i * 128 + l * 8);
                addrow(a0, a1, u0);
            }
        }
        uint4 uh;
        uh.x = pkbf(a0.x, a0.y);
        uh.y = pkbf(a0.z, a0.w);
        uh.z = pkbf(a1.x, a1.y);
        uh.w = pkbf(a1.z, a1.w);
        *(uint4*)&As[r][l * 8] = uh;
    }
    __syncthreads();

    const int w    = tid >> 6;
    const int lane = tid & 63;
    const int ln   = lane & 15;
    const int lq   = lane >> 4;
    const int c0   = w * 32;

    float4v acc[2][2];
    #pragma unroll
    for (int nt = 0; nt < 2; nt++) {
        const float bv = bias[c0 + nt * 16 + ln];
        #pragma unroll
        for (int mt = 0; mt < 2; mt++) acc[mt][nt] = (float4v){bv, bv, bv, bv};
    }

    #pragma unroll
    for (int kc = 0; kc < 4; kc++) {
        const size_t b0 = (size_t)(c0 + ln) * 128 + kc * 32 + lq * 8;
        const size_t b1 = (size_t)(c0 + 16 + ln) * 128 + kc * 32 + lq * 8;
        const short8v bh0 = *(const short8v*)&Wh[b0];
        const short8v bl0 = *(const short8v*)&Wl[b0];
        const short8v bh1 = *(const short8v*)&Wh[b1];
        const short8v bl1 = *(const short8v*)&Wl[b1];
        #pragma unroll
        for (int mt = 0; mt < 2; mt++) {
            const short8v ah = *(const short8v*)&As[mt * 16 + ln][kc * 32 + lq * 8];
            acc[mt][0] = __builtin_amdgcn_mfma_f32_16x16x32_bf16(ah, bh0, acc[mt][0], 0, 0, 0);
            acc[mt][0] = __builtin_amdgcn_mfma_f32_16x16x32_bf16(ah, bl0, acc[mt][0], 0, 0, 0);
            acc[mt][1] = __builtin_amdgcn_mfma_f32_16x16x32_bf16(ah, bh1, acc[mt][1], 0, 0, 0);
            acc[mt][1] = __builtin_amdgcn_mfma_f32_16x16x32_bf16(ah, bl1, acc[mt][1], 0, 0, 0);
        }
    }

    #pragma unroll
    for (int mt = 0; mt < 2; mt++) {
        #pragma unroll
        for (int nt = 0; nt < 2; nt++) {
            const int colv = c0 + nt * 16 + ln;
            #pragma unroll
            for (int i = 0; i < 4; i++) {
                const int row = row0 + mt * 16 + lq * 4 + i;
                if (row < N)
                    outb[(size_t)row * 128 + colv] = f2bf(acc[mt][nt][i]);
            }
        }
    }

    // BN stats partials (pre-activation z); wave owns its 32 cols
    #pragma unroll
    for (int nt = 0; nt < 2; nt++) {
        float s = 0.f, q = 0.f;
        #pragma unroll
        for (int mt = 0; mt < 2; mt++) {
            #pragma unroll
            for (int i = 0; i < 4; i++) {
                const int row = row0 + mt * 16 + lq * 4 + i;
                if (row < N) { const float v = acc[mt][nt][i]; s += v; q += v * v; }
            }
        }
        s += __shfl_xor(s, 16); s += __shfl_xor(s, 32);
        q += __shfl_xor(q, 16); q += __shfl_xor(q, 32);
        if (lq == 0) {
            const int colv = c0 + nt * 16 + ln;
            part[(size_t)colv * gridDim.x + blockIdx.x] = s;
            part[(size_t)(128 + colv) * gridDim.x + blockIdx.x] = q;
        }
    }
}

// ---------------------------------------------------------------------------
// Streaming GEMM (lin, gemm2): 128-row tile, acc[8][2].
// flags: 1=BN apply+relu on staged input, 2=relu out, 64=bf16 input.
// ---------------------------------------------------------------------------
__global__ __launch_bounds__(256) void gemm_stream(
    const float* __restrict__ Ain32, const unsigned short* __restrict__ AinB,
    const unsigned short* __restrict__ Wh, const unsigned short* __restrict__ Wl,
    const float* __restrict__ bias, const float* __restrict__ ss,
    unsigned short* __restrict__ outb, int N, int flags)
{
    __shared__ __align__(16) unsigned short As[128][136];
    const int tid = threadIdx.x;
    const int row0 = blockIdx.x * 128;

    if (flags & 64) {
        for (int i = tid; i < 128 * 16; i += 256) {
            const int r = i >> 4, c8 = i & 15;
            const int row = row0 + r;
            uint4 u = make_uint4(0, 0, 0, 0);
            if (row < N) {
                u = *(const uint4*)(AinB + (size_t)row * 128 + c8 * 8);
                if (flags & 1) {
                    float4 v0, v1;
                    v0.x = bfu_lo(u.x); v0.y = bfu_hi(u.x);
                    v0.z = bfu_lo(u.y); v0.w = bfu_hi(u.y);
                    v1.x = bfu_lo(u.z); v1.y = bfu_hi(u.z);
                    v1.z = bfu_lo(u.w); v1.w = bfu_hi(u.w);
                    const float4 sc0 = ((const float4*)ss)[c8 * 2];
                    const float4 sc1 = ((const float4*)ss)[c8 * 2 + 1];
                    const float4 sh0 = ((const float4*)(ss + 128))[c8 * 2];
                    const float4 sh1 = ((const float4*)(ss + 128))[c8 * 2 + 1];
                    v0.x = fmaxf(v0.x * sc0.x + sh0.x, 0.f);
                    v0.y = fmaxf(v0.y * sc0.y + sh0.y, 0.f);
                    v0.z = fmaxf(v0.z * sc0.z + sh0.z, 0.f);
                    v0.w = fmaxf(v0.w * sc0.w + sh0.w, 0.f);
                    v1.x = fmaxf(v1.x * sc1.x + sh1.x, 0.f);
                    v1.y = fmaxf(v1.y * sc1.y + sh1.y, 0.f);
                    v1.z = fmaxf(v1.z * sc1.z + sh1.z, 0.f);
                    v1.w = fmaxf(v1.w * sc1.w + sh1.w, 0.f);
                    u.x = pkbf(v0.x, v0.y);
                    u.y = pkbf(v0.z, v0.w);
                    u.z = pkbf(v1.x, v1.y);
                    u.w = pkbf(v1.z, v1.w);
                }
            }
            *(uint4*)&As[r][c8 * 8] = u;
        }
    } else {
        for (int i = tid; i < 128 * 32; i += 256) {
            const int r = i >> 5, c4 = i & 31;
            const int row = row0 + r;
            float4 v = make_float4(0.f, 0.f, 0.f, 0.f);
            if (row < N) v = ((const float4*)(Ain32 + (size_t)row * 128))[c4];
            uint2 uh;
            uh.x = pkbf(v.x, v.y);
            uh.y = pkbf(v.z, v.w);
            *(uint2*)&As[r][c4 * 4] = uh;
        }
    }
    __syncthreads();

    const int w    = tid >> 6;
    const int lane = tid & 63;
    const int ln   = lane & 15;
    const int lq   = lane >> 4;
    const int c0   = w * 32;

    float4v acc[8][2];
    #pragma unroll
    for (int nt = 0; nt < 2; nt++) {
        const float bv = bias[c0 + nt * 16 + ln];
        #pragma unroll
        for (int mt = 0; mt < 8; mt++) acc[mt][nt] = (float4v){bv, bv, bv, bv};
    }

    #pragma unroll
    for (int kc = 0; kc < 4; kc++) {
        const size_t b0 = (size_t)(c0 + ln) * 128 + kc * 32 + lq * 8;
        const size_t b1 = (size_t)(c0 + 16 + ln) * 128 + kc * 32 + lq * 8;
        const short8v bh0 = *(const short8v*)&Wh[b0];
        const short8v bl0 = *(const short8v*)&Wl[b0];
        const short8v bh1 = *(const short8v*)&Wh[b1];
        const short8v bl1 = *(const short8v*)&Wl[b1];
        #pragma unroll
        for (int mt = 0; mt < 8; mt++) {
            const short8v ah = *(const short8v*)&As[mt * 16 + ln][kc * 32 + lq * 8];
            acc[mt][0] = __builtin_amdgcn_mfma_f32_16x16x32_bf16(ah, bh0, acc[mt][0], 0, 0, 0);
            acc[mt][0] = __builtin_amdgcn_mfma_f32_16x16x32_bf16(ah, bl0, acc[mt][0], 0, 0, 0);
            acc[mt][1] = __builtin_amdgcn_mfma_f32_16x16x32_bf16(ah, bh1, acc[mt][1], 0, 0, 0);
            acc[mt][1] = __builtin_amdgcn_mfma_f32_16x16x32_bf16(ah, bl1, acc[mt][1], 0, 0, 0);
        }
    }

    #pragma unroll
    for (int mt = 0; mt < 8; mt++) {
        #pragma unroll
        for (int nt = 0; nt < 2; nt++) {
            const int colv = c0 + nt * 16 + ln;
            #pragma unroll
            for (int i = 0; i < 4; i++) {
                const int row = row0 + mt * 16 + lq * 4 + i;
                if (row < N) {
                    float v = acc[mt][nt][i];
                    if (flags & 2) v = fmaxf(v, 0.f);
                    outb[(size_t)row * 128 + colv] = f2bf(v);
                }
            }
        }
    }
}

// ---------------------------------------------------------------------------
// BN finalize: reduce partials -> scale[c], shift[c]. grid=128 (1/channel).
// ---------------------------------------------------------------------------
__global__ __launch_bounds__(256) void bn_finalize(
    const float* __restrict__ part, int nblk, float invN,
    const float* __restrict__ gamma, const float* __restrict__ beta,
    float* __restrict__ ss)
{
    __shared__ float shs[256], shq[256];
    const int c = blockIdx.x, t = threadIdx.x;
    float s = 0.f, q = 0.f;
    for (int b = t; b < nblk; b += 256) {
        s += part[(size_t)c * nblk + b];
        q += part[(size_t)(128 + c) * nblk + b];
    }
    shs[t] = s; shq[t] = q;
    __syncthreads();
    for (int o = 128; o > 0; o >>= 1) {
        if (t < o) { shs[t] += shs[t + o]; shq[t] += shq[t + o]; }
        __syncthreads();
    }
    if (t == 0) {
        const float mu = shs[0] * invN;
        const float var = shq[0] * invN - mu * mu;
        const float sc = rsqrtf(fmaxf(var, 0.f) + 1e-5f) * gamma[c];
        ss[c] = sc;
        ss[128 + c] = beta[c] - mu * sc;
    }
}

// ---------------------------------------------------------------------------
// Classifier: out[e] = dot(hb[ia[e]], hb[ib[e]]). 2 edges per 16-lane group
// per iteration (4 independent 16B loads in flight), float2 store.
// ---------------------------------------------------------------------------
__global__ __launch_bounds__(256) void edge_dot(
    const unsigned short* __restrict__ hb, const int* __restrict__ ia,
    const int* __restrict__ ib, float* __restrict__ out, int EL)
{
    const int stride = gridDim.x * blockDim.x;
    const int npair = (EL + 1) >> 1;
    const long long total = (long long)npair * 16;
    for (long long i = (long long)blockIdx.x * blockDim.x + threadIdx.x; i < total; i += stride) {
        const int p = (int)(i >> 4);
        const int l = (int)(i & 15);
        const int e0 = p * 2;
        const int e1 = e0 + 1;
        const int a0i = ia[e0], b0i = ib[e0];
        const uint4 ua0 = *(const uint4*)(hb + (size_t)a0i * 128 + l * 8);
        const uint4 ub0 = *(const uint4*)(hb + (size_t)b0i * 128 + l * 8);
        uint4 ua1 = make_uint4(0, 0, 0, 0), ub1 = make_uint4(0, 0, 0, 0);
        const bool has1 = (e1 < EL);
        if (has1) {
            const int a1i = ia[e1], b1i = ib[e1];
            ua1 = *(const uint4*)(hb + (size_t)a1i * 128 + l * 8);
            ub1 = *(const uint4*)(hb + (size_t)b1i * 128 + l * 8);
        }
        float d0 = bfu_lo(ua0.x) * bfu_lo(ub0.x) + bfu_hi(ua0.x) * bfu_hi(ub0.x)
                 + bfu_lo(ua0.y) * bfu_lo(ub0.y) + bfu_hi(ua0.y) * bfu_hi(ub0.y)
                 + bfu_lo(ua0.z) * bfu_lo(ub0.z) + bfu_hi(ua0.z) * bfu_hi(ub0.z)
                 + bfu_lo(ua0.w) * bfu_lo(ub0.w) + bfu_hi(ua0.w) * bfu_hi(ub0.w);
        float d1 = bfu_lo(ua1.x) * bfu_lo(ub1.x) + bfu_hi(ua1.x) * bfu_hi(ub1.x)
                 + bfu_lo(ua1.y) * bfu_lo(ub1.y) + bfu_hi(ua1.y) * bfu_hi(ub1.y)
                 + bfu_lo(ua1.z) * bfu_lo(ub1.z) + bfu_hi(ua1.z) * bfu_hi(ub1.z)
                 + bfu_lo(ua1.w) * bfu_lo(ub1.w) + bfu_hi(ua1.w) * bfu_hi(ub1.w);
        d0 += __shfl_xor(d0, 1); d1 += __shfl_xor(d1, 1);
        d0 += __shfl_xor(d0, 2); d1 += __shfl_xor(d1, 2);
        d0 += __shfl_xor(d0, 4); d1 += __shfl_xor(d1, 4);
        d0 += __shfl_xor(d0, 8); d1 += __shfl_xor(d1, 8);
        if (l == 0) {
            if (has1) *(float2*)(out + e0) = make_float2(d0, d1);
            else      out[e0] = d0;
        }
    }
}

extern "C" void kernel_launch(void* const* d_in, const int* in_sizes, int n_in,
                              void* d_out, int out_size, void* d_ws, size_t ws_size,
                              hipStream_t stream)
{
    const float* x     = (const float*)d_in[0];
    const float* lin_w = (const float*)d_in[1];
    const float* lin_b = (const float*)d_in[2];
    const float* W1    = (const float*)d_in[3];
    const float* b1    = (const float*)d_in[4];
    const float* gamma = (const float*)d_in[5];
    const float* beta  = (const float*)d_in[6];
    const float* W2    = (const float*)d_in[7];
    const float* b2    = (const float*)d_in[8];
    const int*   ei    = (const int*)d_in[9];
    const int*   eli   = (const int*)d_in[10];
    float* out = (float*)d_out;

    const int N  = in_sizes[0] / 128;
    const int E  = in_sizes[9] / 2;
    const int EL = in_sizes[10] / 2;
    const size_t nd = (size_t)N * 128;
    const int nbc = (N + 1023) >> 10;            // 1024-node chunks
    const int g_grid = (N + 31) / 32;            // gather-gemm grid (32-row tiles)
    const int s_grid = (N + 127) / 128;          // streaming-gemm grid

    // ws: hbH | hbZ | deg | rowptr | cnt | ctot | chunkBase | temp | col | wts | part | ss
    unsigned short* hbH = (unsigned short*)d_ws;
    unsigned short* hbZ = hbH + nd;
    int*   deg    = (int*)(hbZ + nd);
    int*   rowptr = deg + N;
    int*   cnt    = rowptr + N;                  // [nbc][NBLK_SORT]
    int*   ctot   = cnt + (size_t)nbc * NBLK_SORT;
    int*   chunkBase = ctot + nbc;
    int*   temp   = chunkBase + nbc + 1;
    int*   col    = temp + E;
    unsigned short* wt_hi = (unsigned short*)(col + E);
    unsigned short* wt_lo = wt_hi + 7 * 16384;
    float* part   = (float*)(wt_lo + 7 * 16384);
    float* ss     = part + (size_t)256 * g_grid;

    const float invN = 1.0f / (float)N;

    // ---- weight prep + bucketed CSR build ----
    prep_w<<<448, 256, 0, stream>>>(lin_w, W1, W2, wt_hi, wt_lo);
    chunk_count<<<NBLK_SORT, 256, 0, stream>>>(ei + E, cnt, E, nbc);
    scan_blocks<<<nbc, 512, 0, stream>>>(cnt, ctot);
    scan_ctot<<<1, 64, 0, stream>>>(ctot, chunkBase, nbc);
    bucket_scatter<<<NBLK_SORT, 256, 0, stream>>>(ei, ei + E, cnt, chunkBase, temp, E, nbc);
    chunk_place<<<nbc, 256, 0, stream>>>(temp, chunkBase, col, deg, rowptr, N);

    // ---- h = x @ lin_w + lin_b  -> hbH (bf16) ----
    gemm_stream<<<s_grid, 256, 0, stream>>>(x, nullptr, wt_hi, wt_lo, lin_b, ss,
                                            hbH, N, 0);

    for (int l = 0; l < 3; l++) {
        const unsigned short* w1h = wt_hi + (size_t)(1 + l) * 16384;
        const unsigned short* w1l = wt_lo + (size_t)(1 + l) * 16384;
        const unsigned short* w2h = wt_hi + (size_t)(4 + l) * 16384;
        const unsigned short* w2l = wt_lo + (size_t)(4 + l) * 16384;
        // z = (h + agg) @ W1 + b1 : gather from hbH, write hbZ, BN partials
        gemm_gather<<<g_grid, 256, 0, stream>>>(hbH, rowptr, deg, col,
                                                w1h, w1l, b1 + (size_t)l * 128,
                                                hbZ, part, N);
        bn_finalize<<<128, 256, 0, stream>>>(part, g_grid, invN,
                                             gamma + (size_t)l * 128,
                                             beta + (size_t)l * 128, ss);
        // h = relu(bn(z) @ W2 + b2) : stage hbZ + BN + relu, write hbH
        gemm_stream<<<s_grid, 256, 0, stream>>>(nullptr, hbZ, w2h, w2l,
                                                b2 + (size_t)l * 128, ss,
                                                hbH, N, 1 | 2 | 64);
    }

    edge_dot<<<8192, 256, 0, stream>>>(hbH, eli, eli + EL, out, EL);
}